// Round 6
// baseline (6890.237 us; speedup 1.0000x reference)
//
#include <hip/hip_runtime.h>

// Persistent-LSTM, round 10: fat workgroups — 4x fewer barrier participants.
//   B=64,S=512,D=256,H=512. 4 teams x 16 batches; team = 16 WGs x 512 thr
//   (8 waves). Wave owns 16 gate rows (4 h-idx x 4 gates), W hi/lo bf16
//   resident. gates = [x_t,h_{t-1}] @ W^T via mfma_f32_16x16x32_bf16.
//
//   Falsification ledger (dur ~9.4us/step flat through all of):
//     R3->R5: sync scope + locality (FETCH 399->62MB)      -> not transport
//     R8:     out[] HBM store drain moved off chain         -> not store ack
//     R9:     busy-burn activity (VALUBusy 3.3->18.5%)      -> not DPM clock
//   Remaining axis: barrier SHAPE. Step time = max over 64 WGs of
//   (detect+work+drain+store) x 512 rounds; per-WG jitter tail paid fully
//   every round. R10 keeps algorithm/transport identical and only changes
//   structure: 64 WGs x 2 waves -> 16 WGs x 8 waves per team. Intra-WG sync
//   becomes HW __syncthreads; inter-WG flags 64 -> 16 dwords (1 cache line);
//   tail = max-over-16; 8 waves/CU share identical x/h lines in L1.
//   Burners removed (R9: harmful). LDS out-staging kept (R8: neutral-good).

#define NB 64
#define NS 512
#define ND 256
#define NH 512
#define FLAG_MAGIC 0x41000000
#define PLANE_ELEMS (NB * NH)   // 32768 elems, 64 KiB/plane
#define NWG 16                  // workgroups per team
#define NWORKB 64               // worker blocks total (4 teams x 16 WGs)

typedef __bf16 bf16x8 __attribute__((ext_vector_type(8)));
typedef float  f32x4  __attribute__((ext_vector_type(4)));

union Frag {
  bf16x8 v;
  unsigned long long u[2];
  __bf16 e[8];
};

__device__ __forceinline__ float bf2f(__bf16 b) {
  unsigned short us = __builtin_bit_cast(unsigned short, b);
  unsigned int ui = ((unsigned int)us) << 16;
  return __builtin_bit_cast(float, ui);
}

__device__ __forceinline__ void hilo8(const float* vals, Frag& fh, Frag& fl) {
#pragma unroll
  for (int j = 0; j < 8; ++j) {
    __bf16 hi = (__bf16)vals[j];
    float r = vals[j] - bf2f(hi);
    fh.e[j] = hi;
    fl.e[j] = (__bf16)r;
  }
}

__device__ __forceinline__ float fsigmoid(float x) {
  return 1.0f / (1.0f + __expf(-x));
}
__device__ __forceinline__ float ftanh(float x) {
  float t = fminf(fmaxf(2.0f * x, -30.0f), 30.0f);
  float e = __expf(t);
  return (e - 1.0f) / (e + 1.0f);
}

// L1-bypass load served by the XCD L2 (the coherence point vs plain stores
// from other CUs on the SAME XCD). gfx950 spelling: sc0.
__device__ __forceinline__ int poll_sc0(const int* p) {
  int v;
  asm volatile("global_load_dword %0, %1, off sc0\n\ts_waitcnt vmcnt(0)"
               : "=&v"(v) : "v"(p) : "memory");
  return v;
}

template<bool FAST>
__device__ __forceinline__ void run_lstm(
    const float* __restrict__ x, const float* __restrict__ h0,
    const float* __restrict__ c0, float* __restrict__ out,
    int* flagsT, int* flagsBT,
    unsigned short* __restrict__ hring, unsigned short* __restrict__ lring,
    const bf16x8* Ahi, const bf16x8* Alo, const float* bias,
    float (*s_out)[512],
    int tid, int lane, int wg, int quad, int myb, int myh)
{
  float c_st  = c0[myb * NH + myh];
  float h_val = 0.0f;

#pragma unroll 1
  for (int t = 0; t < NS; ++t) {
    // ---- x-projection partial: bias + x_t @ Wih^T (overlaps the wait) -----
    float4 xf[16];
    const float* xr = x + (myb * NS + t) * ND + quad * 8;
#pragma unroll
    for (int c = 0; c < 8; ++c) {
      xf[2 * c]     = *(const float4*)(xr + 32 * c);
      xf[2 * c + 1] = *(const float4*)(xr + 32 * c + 4);
    }
    f32x4 a_hh = {bias[0], bias[1], bias[2], bias[3]};
    f32x4 a_hl = {0.f, 0.f, 0.f, 0.f};
    f32x4 a_lh = {0.f, 0.f, 0.f, 0.f};
#pragma unroll
    for (int c = 0; c < 8; ++c) {
      float vals[8] = {xf[2*c].x, xf[2*c].y, xf[2*c].z, xf[2*c].w,
                       xf[2*c+1].x, xf[2*c+1].y, xf[2*c+1].z, xf[2*c+1].w};
      Frag bh, bl;
      hilo8(vals, bh, bl);
      a_hh = __builtin_amdgcn_mfma_f32_16x16x32_bf16(Ahi[c], bh.v, a_hh, 0, 0, 0);
      a_hl = __builtin_amdgcn_mfma_f32_16x16x32_bf16(Ahi[c], bl.v, a_hl, 0, 0, 0);
      a_lh = __builtin_amdgcn_mfma_f32_16x16x32_bf16(Alo[c], bh.v, a_lh, 0, 0, 0);
    }

    // ---- h recurrence -----------------------------------------------------
    if (t > 0) {
      // wait for all 16 team WGs to finish step t-1 (flags: one 64B line)
      int spin = 0;
      while (true) {
        int fl;
        if (FAST) {
          fl = poll_sc0(flagsT + (lane & 15));   // XCD-L2 hit
          if ((++spin & 8191) == 0) {            // watchdog: L3 backup copy
            int fb = __hip_atomic_load(flagsBT + (lane & 15), __ATOMIC_RELAXED,
                                       __HIP_MEMORY_SCOPE_AGENT);
            if (fb > fl) fl = fb;
          }
        } else {
          fl = __hip_atomic_load(flagsT + (lane & 15), __ATOMIC_RELAXED,
                                 __HIP_MEMORY_SCOPE_AGENT);
        }
        unsigned int d = (unsigned int)(fl - FLAG_MAGIC);
        if (__all(d >= (unsigned int)t && d <= 512u)) break;
        __builtin_amdgcn_s_sleep(1);
      }
      asm volatile("" ::: "memory");  // no h load hoisted above the poll

      // fresh addresses each step -> plain loads are coherent
      const unsigned short* hbp = hring + (t - 1) * PLANE_ELEMS + myb * NH + quad * 8;
      const unsigned short* lbp = lring + (t - 1) * PLANE_ELEMS + myb * NH + quad * 8;
#pragma unroll
      for (int c = 8; c < 24; ++c) {
        int off = 32 * (c - 8);
        Frag bh, bl;
        bh.v = *(const bf16x8*)(hbp + off);
        bl.v = *(const bf16x8*)(lbp + off);
        a_hh = __builtin_amdgcn_mfma_f32_16x16x32_bf16(Ahi[c], bh.v, a_hh, 0, 0, 0);
        a_hl = __builtin_amdgcn_mfma_f32_16x16x32_bf16(Ahi[c], bl.v, a_hl, 0, 0, 0);
        a_lh = __builtin_amdgcn_mfma_f32_16x16x32_bf16(Alo[c], bh.v, a_lh, 0, 0, 0);
      }
    } else {
      const float* hr = h0 + myb * NH + quad * 8;
#pragma unroll
      for (int c = 8; c < 24; ++c) {
        int off = 32 * (c - 8);
        float4 f0 = *(const float4*)(hr + off);
        float4 f1 = *(const float4*)(hr + off + 4);
        float vals[8] = {f0.x, f0.y, f0.z, f0.w, f1.x, f1.y, f1.z, f1.w};
        Frag bh, bl;
        hilo8(vals, bh, bl);
        a_hh = __builtin_amdgcn_mfma_f32_16x16x32_bf16(Ahi[c], bh.v, a_hh, 0, 0, 0);
        a_hl = __builtin_amdgcn_mfma_f32_16x16x32_bf16(Ahi[c], bl.v, a_hl, 0, 0, 0);
        a_lh = __builtin_amdgcn_mfma_f32_16x16x32_bf16(Alo[c], bh.v, a_lh, 0, 0, 0);
      }
    }

    // ---- LSTM cell (lane-local) -------------------------------------------
    float pre_i = a_hh[0] + a_hl[0] + a_lh[0];
    float pre_f = a_hh[1] + a_hl[1] + a_lh[1];
    float pre_g = a_hh[2] + a_hl[2] + a_lh[2];
    float pre_o = a_hh[3] + a_hl[3] + a_lh[3];
    float gi = fsigmoid(pre_i);
    float gf = fsigmoid(pre_f);
    float gg = ftanh(pre_g);
    float go = fsigmoid(pre_o);
    c_st  = gf * c_st + gi * gg;
    h_val = go * ftanh(c_st);

    // ---- stage h into LDS (thread-local slot; no HBM store in chain) ------
    s_out[t & 31][tid] = h_val;

    // ---- publish h_t (hi/lo bf16, packed u32 per h-pair) --------------------
    __bf16 hh = (__bf16)h_val;
    float  rr = h_val - bf2f(hh);
    __bf16 hl = (__bf16)rr;
    unsigned int uh = (unsigned int)__builtin_bit_cast(unsigned short, hh);
    unsigned int ul = (unsigned int)__builtin_bit_cast(unsigned short, hl);
    unsigned int ph = (unsigned int)__shfl_xor((int)uh, 16, 64);
    unsigned int pl = (unsigned int)__shfl_xor((int)ul, 16, 64);
    if ((quad & 1) == 0) {
      int eoff = t * PLANE_ELEMS + myb * NH + myh;
      if (FAST) {
        __hip_atomic_store((unsigned int*)(hring + eoff), uh | (ph << 16),
                           __ATOMIC_RELAXED, __HIP_MEMORY_SCOPE_WORKGROUP);
        __hip_atomic_store((unsigned int*)(lring + eoff), ul | (pl << 16),
                           __ATOMIC_RELAXED, __HIP_MEMORY_SCOPE_WORKGROUP);
      } else {
        __hip_atomic_store((unsigned int*)(hring + eoff), uh | (ph << 16),
                           __ATOMIC_RELAXED, __HIP_MEMORY_SCOPE_AGENT);
        __hip_atomic_store((unsigned int*)(lring + eoff), ul | (pl << 16),
                           __ATOMIC_RELAXED, __HIP_MEMORY_SCOPE_AGENT);
      }
    }

    // order h stores (L2 ack in FAST, L3 ack in slow) before the flag.
    asm volatile("s_waitcnt vmcnt(0)" ::: "memory");
    __syncthreads();   // 8 waves, HW barrier
    if (tid == 0) {
      if (FAST) {
        __hip_atomic_store(flagsT + wg, FLAG_MAGIC + t + 1,
                           __ATOMIC_RELAXED, __HIP_MEMORY_SCOPE_WORKGROUP);
        __hip_atomic_store(flagsBT + wg, FLAG_MAGIC + t + 1,
                           __ATOMIC_RELAXED, __HIP_MEMORY_SCOPE_AGENT);
      } else {
        __hip_atomic_store(flagsT + wg, FLAG_MAGIC + t + 1,
                           __ATOMIC_RELAXED, __HIP_MEMORY_SCOPE_AGENT);
      }
    }

    // ---- bulk flush every 32 steps, AFTER the flag ------------------------
    if ((t & 31) == 31) {
      int t0 = t - 31;
#pragma unroll 4
      for (int ti = 0; ti < 32; ++ti)
        out[(myb * NS + t0 + ti) * NH + myh] = s_out[ti][tid];
    }
  }

  const int obase = NB * NS * NH;
  out[obase + myb * NH + myh] = h_val;
  out[obase + NB * NH + myb * NH + myh] = c_st;
}

__global__ __launch_bounds__(512, 1)
void lstm_l2(const float* __restrict__ x,
             const float* __restrict__ Wih,
             const float* __restrict__ Whh,
             const float* __restrict__ bih,
             const float* __restrict__ bhh,
             const float* __restrict__ h0,
             const float* __restrict__ c0,
             float* __restrict__ out,
             int* flags, int* flagsB, int* ready, unsigned int* masks,
             unsigned short* __restrict__ hring,
             unsigned short* __restrict__ lring)
{
  const int b = blockIdx.x;
  if ((b & 7) >= 4) return;       // shadow blocks: fill XCDs 4-7's round-robin
  const int team = b & 7;         // 0..3 -> one XCD per team (if mapping holds)
  const int wg   = b >> 3;        // 0..15
  const int tid  = threadIdx.x;
  const int lane = tid & 63;
  const int wv   = tid >> 6;      // 0..7
  const int l15  = lane & 15;
  const int quad = lane >> 4;
  const int hb   = wg * 32 + wv * 4;
  const int myb  = team * 16 + l15;
  const int myh  = hb + quad;

  int* flagsT  = flags  + team * NWG;
  int* flagsBT = flagsB + team * NWG;

  // ---- placement handshake (one-time): which XCD is this block on? --------
  int xcc;
  asm volatile("s_getreg_b32 %0, hwreg(HW_REG_XCC_ID)" : "=s"(xcc));
  if (tid == 0) {
    __hip_atomic_fetch_or(&masks[team], 1u << (xcc & 31),
                          __ATOMIC_RELAXED, __HIP_MEMORY_SCOPE_AGENT);
    __hip_atomic_fetch_add(ready, 1, __ATOMIC_RELEASE, __HIP_MEMORY_SCOPE_AGENT);
  }

  // ---- persistent A operand: W rows, compensated hi/lo (overlaps handshake)
  const int jA = l15 >> 2;
  const int gA = l15 & 3;
  const int rA = gA * NH + hb + jA;
  bf16x8 Ahi[24], Alo[24];
  {
    const float* wi = Wih + rA * ND;
    const float* wh = Whh + rA * NH;
#pragma unroll
    for (int c = 0; c < 24; ++c) {
      int k0 = c * 32 + quad * 8;
      const float* src = (c < 8) ? (wi + k0) : (wh + (k0 - 256));
      float4 f0 = *(const float4*)(src);
      float4 f1 = *(const float4*)(src + 4);
      float vals[8] = {f0.x, f0.y, f0.z, f0.w, f1.x, f1.y, f1.z, f1.w};
      Frag fh, fl;
      hilo8(vals, fh, fl);
      Ahi[c] = fh.v;
      Alo[c] = fl.v;
    }
  }

  float bias[4];
#pragma unroll
  for (int g = 0; g < 4; ++g)
    bias[g] = bih[g * NH + myh] + bhh[g * NH + myh];

  // ---- 64KB LDS staging for out[] (thread-local slots) --------------------
  __shared__ float s_out[32][512];

  // ---- finish handshake: fast iff my whole team saw ONE xcc_id ------------
  __shared__ int s_fast;
  if (tid == 0) {
    while (__hip_atomic_load(ready, __ATOMIC_ACQUIRE,
                             __HIP_MEMORY_SCOPE_AGENT) < NWORKB)
      __builtin_amdgcn_s_sleep(2);
    unsigned int m = __hip_atomic_load(&masks[team], __ATOMIC_RELAXED,
                                       __HIP_MEMORY_SCOPE_AGENT);
    s_fast = (__popc(m) == 1) ? 1 : 0;
  }
  __syncthreads();

  if (s_fast)
    run_lstm<true>(x, h0, c0, out, flagsT, flagsBT, hring, lring,
                   Ahi, Alo, bias, s_out, tid, lane, wg, quad, myb, myh);
  else
    run_lstm<false>(x, h0, c0, out, flagsT, flagsBT, hring, lring,
                    Ahi, Alo, bias, s_out, tid, lane, wg, quad, myb, myh);
}

extern "C" void kernel_launch(void* const* d_in, const int* in_sizes, int n_in,
                              void* d_out, int out_size, void* d_ws, size_t ws_size,
                              hipStream_t stream) {
  const float* x   = (const float*)d_in[0];
  const float* Wih = (const float*)d_in[1];
  const float* Whh = (const float*)d_in[2];
  const float* bih = (const float*)d_in[3];
  const float* bhh = (const float*)d_in[4];
  const float* h0  = (const float*)d_in[5];
  const float* c0  = (const float*)d_in[6];
  float* out = (float*)d_out;

  char* ws = (char*)d_ws;
  // layout: [0,1024) flags  [1024] ready  [1028,1044) masks  [2048,3072) flagsB
  //         [4096, +33.5MB) hring  [.., +33.5MB) lring   (~67.1 MB total)
  int* flags  = (int*)ws;
  int* ready  = (int*)(ws + 1024);
  unsigned int* masks = (unsigned int*)(ws + 1028);
  int* flagsB = (int*)(ws + 2048);
  const size_t ringBytes = (size_t)NS * PLANE_ELEMS * sizeof(unsigned short);
  unsigned short* hring = (unsigned short*)(ws + 4096);
  unsigned short* lring = (unsigned short*)(ws + 4096 + ringBytes);

  // zero flag page each launch: kills cross-launch flag/counter staleness
  (void)hipMemsetAsync(ws, 0, 4096, stream);

  lstm_l2<<<dim3(128), dim3(512), 0, stream>>>(
      x, Wih, Whh, bih, bhh, h0, c0, out, flags, flagsB, ready, masks,
      hring, lring);
}

// Round 10
// 4780.579 us; speedup vs baseline: 1.4413x; 1.4413x over previous
//
#include <hip/hip_runtime.h>

// Persistent-LSTM, round 14: R13 compile-fixed (s_sleep needs const arg).
//   B=64,S=512,D=256,H=512. 4 teams x 16 batches; team = 64 WGs x 128 thr.
//   Wave owns 16 gate rows (4 h-idx x 4 gates), W hi/lo bf16 resident.
//   gates = [x_t,h_{t-1}] @ W^T via mfma_f32_16x16x32_bf16 (compensated hi/lo).
//
//   Theory (unchanged, unmeasured): poll-fabric contention. ~128 waves/team
//   x 64-lane gathers on 4 flag lines every ~320cy => flag store + observe
//   queue behind hundreds of in-flight polls at the line service point
//   (MALL or L2 -- explains R3==R5 scope invariance). Fix: (1) only wave0
//   polls, wave1 waits at the HW __syncthreads (pollers 128->64/team);
//   (2) exponential backoff via constant-arg s_sleep 1/2/4/8 (poll rate ~8x
//   down, detect quantization capped at 512cy). Everything else
//   byte-identical to R8 (passed, 4802us).

#define NB 64
#define NS 512
#define ND 256
#define NH 512
#define FLAG_MAGIC 0x41000000
#define PLANE_ELEMS (NB * NH)   // 32768 elems, 64 KiB/plane
#define NWORK 256               // worker blocks: 4 teams x 64 WGs

typedef __bf16 bf16x8 __attribute__((ext_vector_type(8)));
typedef float  f32x4  __attribute__((ext_vector_type(4)));

union Frag {
  bf16x8 v;
  unsigned long long u[2];
  __bf16 e[8];
};

__device__ __forceinline__ float bf2f(__bf16 b) {
  unsigned short us = __builtin_bit_cast(unsigned short, b);
  unsigned int ui = ((unsigned int)us) << 16;
  return __builtin_bit_cast(float, ui);
}

__device__ __forceinline__ void hilo8(const float* vals, Frag& fh, Frag& fl) {
#pragma unroll
  for (int j = 0; j < 8; ++j) {
    __bf16 hi = (__bf16)vals[j];
    float r = vals[j] - bf2f(hi);
    fh.e[j] = hi;
    fl.e[j] = (__bf16)r;
  }
}

__device__ __forceinline__ float fsigmoid(float x) {
  return 1.0f / (1.0f + __expf(-x));
}
__device__ __forceinline__ float ftanh(float x) {
  float t = fminf(fmaxf(2.0f * x, -30.0f), 30.0f);
  float e = __expf(t);
  return (e - 1.0f) / (e + 1.0f);
}

// backoff sleep with the constant-argument requirement satisfied
__device__ __forceinline__ void sleep_backoff(int spin) {
  if (spin == 0)      __builtin_amdgcn_s_sleep(1);
  else if (spin == 1) __builtin_amdgcn_s_sleep(2);
  else if (spin == 2) __builtin_amdgcn_s_sleep(4);
  else                __builtin_amdgcn_s_sleep(8);
}

// L1-bypass load served by the XCD L2 (the coherence point vs plain stores
// from other CUs on the SAME XCD). gfx950 spelling: sc0.
__device__ __forceinline__ int poll_sc0(const int* p) {
  int v;
  asm volatile("global_load_dword %0, %1, off sc0\n\ts_waitcnt vmcnt(0)"
               : "=&v"(v) : "v"(p) : "memory");
  return v;
}

template<bool FAST>
__device__ __forceinline__ void run_lstm(
    const float* __restrict__ x, const float* __restrict__ h0,
    const float* __restrict__ c0, float* __restrict__ out,
    int* flagsT, int* flagsBT,
    unsigned short* __restrict__ hring, unsigned short* __restrict__ lring,
    const bf16x8* Ahi, const bf16x8* Alo, const float* bias,
    float (*s_out)[128],
    int tid, int lane, int wv, int wg, int quad, int myb, int myh)
{
  float c_st  = c0[myb * NH + myh];
  float h_val = 0.0f;

#pragma unroll 1
  for (int t = 0; t < NS; ++t) {
    // ---- x-projection partial: bias + x_t @ Wih^T (overlaps the wait) -----
    float4 xf[16];
    const float* xr = x + (myb * NS + t) * ND + quad * 8;
#pragma unroll
    for (int c = 0; c < 8; ++c) {
      xf[2 * c]     = *(const float4*)(xr + 32 * c);
      xf[2 * c + 1] = *(const float4*)(xr + 32 * c + 4);
    }
    f32x4 a_hh = {bias[0], bias[1], bias[2], bias[3]};
    f32x4 a_hl = {0.f, 0.f, 0.f, 0.f};
    f32x4 a_lh = {0.f, 0.f, 0.f, 0.f};
#pragma unroll
    for (int c = 0; c < 8; ++c) {
      float vals[8] = {xf[2*c].x, xf[2*c].y, xf[2*c].z, xf[2*c].w,
                       xf[2*c+1].x, xf[2*c+1].y, xf[2*c+1].z, xf[2*c+1].w};
      Frag bh, bl;
      hilo8(vals, bh, bl);
      a_hh = __builtin_amdgcn_mfma_f32_16x16x32_bf16(Ahi[c], bh.v, a_hh, 0, 0, 0);
      a_hl = __builtin_amdgcn_mfma_f32_16x16x32_bf16(Ahi[c], bl.v, a_hl, 0, 0, 0);
      a_lh = __builtin_amdgcn_mfma_f32_16x16x32_bf16(Alo[c], bh.v, a_lh, 0, 0, 0);
    }

    // ---- h recurrence -----------------------------------------------------
    if (t > 0) {
      // R14: ONE polling wave per WG + exponential backoff. Wave 1 waits at
      // the __syncthreads (HW barrier), halving pollers; backoff cuts poll
      // rate ~8x (cap s_sleep(8)=512cy, bounded detect quantization).
      if (wv == 0) {
        int spin = 0;
        while (true) {
          int fl;
          if (FAST) {
            fl = poll_sc0(flagsT + lane);          // XCD-L2 hit
            if ((spin & 1023) == 1023) {           // watchdog: L3 backup copy
              int fb = __hip_atomic_load(flagsBT + lane, __ATOMIC_RELAXED,
                                         __HIP_MEMORY_SCOPE_AGENT);
              if (fb > fl) fl = fb;
            }
          } else {
            fl = __hip_atomic_load(flagsT + lane, __ATOMIC_RELAXED,
                                   __HIP_MEMORY_SCOPE_AGENT);
          }
          unsigned int d = (unsigned int)(fl - FLAG_MAGIC);
          if (__all(d >= (unsigned int)t && d <= 512u)) break;
          sleep_backoff(spin);
          ++spin;
        }
      }
      __syncthreads();
      asm volatile("" ::: "memory");  // no h load hoisted above the barrier

      // fresh addresses each step -> plain loads are coherent
      const unsigned short* hbp = hring + (t - 1) * PLANE_ELEMS + myb * NH + quad * 8;
      const unsigned short* lbp = lring + (t - 1) * PLANE_ELEMS + myb * NH + quad * 8;
#pragma unroll
      for (int c = 8; c < 24; ++c) {
        int off = 32 * (c - 8);
        Frag bh, bl;
        bh.v = *(const bf16x8*)(hbp + off);
        bl.v = *(const bf16x8*)(lbp + off);
        a_hh = __builtin_amdgcn_mfma_f32_16x16x32_bf16(Ahi[c], bh.v, a_hh, 0, 0, 0);
        a_hl = __builtin_amdgcn_mfma_f32_16x16x32_bf16(Ahi[c], bl.v, a_hl, 0, 0, 0);
        a_lh = __builtin_amdgcn_mfma_f32_16x16x32_bf16(Alo[c], bh.v, a_lh, 0, 0, 0);
      }
    } else {
      const float* hr = h0 + myb * NH + quad * 8;
#pragma unroll
      for (int c = 8; c < 24; ++c) {
        int off = 32 * (c - 8);
        float4 f0 = *(const float4*)(hr + off);
        float4 f1 = *(const float4*)(hr + off + 4);
        float vals[8] = {f0.x, f0.y, f0.z, f0.w, f1.x, f1.y, f1.z, f1.w};
        Frag bh, bl;
        hilo8(vals, bh, bl);
        a_hh = __builtin_amdgcn_mfma_f32_16x16x32_bf16(Ahi[c], bh.v, a_hh, 0, 0, 0);
        a_hl = __builtin_amdgcn_mfma_f32_16x16x32_bf16(Ahi[c], bl.v, a_hl, 0, 0, 0);
        a_lh = __builtin_amdgcn_mfma_f32_16x16x32_bf16(Alo[c], bh.v, a_lh, 0, 0, 0);
      }
    }

    // ---- LSTM cell (lane-local) -------------------------------------------
    float pre_i = a_hh[0] + a_hl[0] + a_lh[0];
    float pre_f = a_hh[1] + a_hl[1] + a_lh[1];
    float pre_g = a_hh[2] + a_hl[2] + a_lh[2];
    float pre_o = a_hh[3] + a_hl[3] + a_lh[3];
    float gi = fsigmoid(pre_i);
    float gf = fsigmoid(pre_f);
    float gg = ftanh(pre_g);
    float go = fsigmoid(pre_o);
    c_st  = gf * c_st + gi * gg;
    h_val = go * ftanh(c_st);

    // ---- stage h into LDS (thread-local slot; no HBM store in chain) ------
    s_out[t & 31][tid] = h_val;

    // ---- publish h_t (hi/lo bf16, packed u32 per h-pair) --------------------
    __bf16 hh = (__bf16)h_val;
    float  rr = h_val - bf2f(hh);
    __bf16 hl = (__bf16)rr;
    unsigned int uh = (unsigned int)__builtin_bit_cast(unsigned short, hh);
    unsigned int ul = (unsigned int)__builtin_bit_cast(unsigned short, hl);
    unsigned int ph = (unsigned int)__shfl_xor((int)uh, 16, 64);
    unsigned int pl = (unsigned int)__shfl_xor((int)ul, 16, 64);
    if ((quad & 1) == 0) {
      int eoff = t * PLANE_ELEMS + myb * NH + myh;
      if (FAST) {
        __hip_atomic_store((unsigned int*)(hring + eoff), uh | (ph << 16),
                           __ATOMIC_RELAXED, __HIP_MEMORY_SCOPE_WORKGROUP);
        __hip_atomic_store((unsigned int*)(lring + eoff), ul | (pl << 16),
                           __ATOMIC_RELAXED, __HIP_MEMORY_SCOPE_WORKGROUP);
      } else {
        __hip_atomic_store((unsigned int*)(hring + eoff), uh | (ph << 16),
                           __ATOMIC_RELAXED, __HIP_MEMORY_SCOPE_AGENT);
        __hip_atomic_store((unsigned int*)(lring + eoff), ul | (pl << 16),
                           __ATOMIC_RELAXED, __HIP_MEMORY_SCOPE_AGENT);
      }
    }

    // order h stores (L2 ack in FAST, L3 ack in slow) before the flag.
    asm volatile("s_waitcnt vmcnt(0)" ::: "memory");
    __syncthreads();
    if (tid == 0) {
      if (FAST) {
        __hip_atomic_store(flagsT + wg, FLAG_MAGIC + t + 1,
                           __ATOMIC_RELAXED, __HIP_MEMORY_SCOPE_WORKGROUP);
        __hip_atomic_store(flagsBT + wg, FLAG_MAGIC + t + 1,
                           __ATOMIC_RELAXED, __HIP_MEMORY_SCOPE_AGENT);
      } else {
        __hip_atomic_store(flagsT + wg, FLAG_MAGIC + t + 1,
                           __ATOMIC_RELAXED, __HIP_MEMORY_SCOPE_AGENT);
      }
    }

    // ---- bulk flush every 32 steps, AFTER the flag ------------------------
    if ((t & 31) == 31) {
      int t0 = t - 31;
#pragma unroll 4
      for (int ti = 0; ti < 32; ++ti)
        out[(myb * NS + t0 + ti) * NH + myh] = s_out[ti][tid];
    }
  }

  const int obase = NB * NS * NH;
  out[obase + myb * NH + myh] = h_val;
  out[obase + NB * NH + myb * NH + myh] = c_st;
}

__global__ __launch_bounds__(128, 1)
void lstm_l2(const float* __restrict__ x,
             const float* __restrict__ Wih,
             const float* __restrict__ Whh,
             const float* __restrict__ bih,
             const float* __restrict__ bhh,
             const float* __restrict__ h0,
             const float* __restrict__ c0,
             float* __restrict__ out,
             int* flags, int* flagsB, int* ready, unsigned int* masks,
             unsigned short* __restrict__ hring,
             unsigned short* __restrict__ lring)
{
  const int b = blockIdx.x;
  if ((b & 7) >= 4) return;       // shadow blocks: fill XCDs 4-7's round-robin
  const int team = b & 7;         // 0..3 -> one XCD per team (if mapping holds)
  const int wg   = b >> 3;        // 0..63
  const int tid  = threadIdx.x;
  const int lane = tid & 63;
  const int wv   = tid >> 6;
  const int l15  = lane & 15;
  const int quad = lane >> 4;
  const int hb   = wg * 8 + wv * 4;
  const int myb  = team * 16 + l15;
  const int myh  = hb + quad;

  int* flagsT  = flags  + team * 64;
  int* flagsBT = flagsB + team * 64;

  // ---- placement handshake (one-time): which XCD is this block on? --------
  int xcc;
  asm volatile("s_getreg_b32 %0, hwreg(HW_REG_XCC_ID)" : "=s"(xcc));
  if (tid == 0) {
    __hip_atomic_fetch_or(&masks[team], 1u << (xcc & 31),
                          __ATOMIC_RELAXED, __HIP_MEMORY_SCOPE_AGENT);
    __hip_atomic_fetch_add(ready, 1, __ATOMIC_RELEASE, __HIP_MEMORY_SCOPE_AGENT);
  }

  // ---- persistent A operand: W rows, compensated hi/lo (overlaps handshake)
  const int jA = l15 >> 2;
  const int gA = l15 & 3;
  const int rA = gA * NH + hb + jA;
  bf16x8 Ahi[24], Alo[24];
  {
    const float* wi = Wih + rA * ND;
    const float* wh = Whh + rA * NH;
#pragma unroll
    for (int c = 0; c < 24; ++c) {
      int k0 = c * 32 + quad * 8;
      const float* src = (c < 8) ? (wi + k0) : (wh + (k0 - 256));
      float4 f0 = *(const float4*)(src);
      float4 f1 = *(const float4*)(src + 4);
      float vals[8] = {f0.x, f0.y, f0.z, f0.w, f1.x, f1.y, f1.z, f1.w};
      Frag fh, fl;
      hilo8(vals, fh, fl);
      Ahi[c] = fh.v;
      Alo[c] = fl.v;
    }
  }

  float bias[4];
#pragma unroll
  for (int g = 0; g < 4; ++g)
    bias[g] = bih[g * NH + myh] + bhh[g * NH + myh];

  // ---- 16KB LDS staging for out[] (thread-local slots) --------------------
  __shared__ float s_out[32][128];

  // ---- finish handshake: fast iff my whole team saw ONE xcc_id ------------
  __shared__ int s_fast;
  if (tid == 0) {
    while (__hip_atomic_load(ready, __ATOMIC_ACQUIRE,
                             __HIP_MEMORY_SCOPE_AGENT) < NWORK)
      __builtin_amdgcn_s_sleep(2);
    unsigned int m = __hip_atomic_load(&masks[team], __ATOMIC_RELAXED,
                                       __HIP_MEMORY_SCOPE_AGENT);
    s_fast = (__popc(m) == 1) ? 1 : 0;
  }
  __syncthreads();

  if (s_fast)
    run_lstm<true>(x, h0, c0, out, flagsT, flagsBT, hring, lring,
                   Ahi, Alo, bias, s_out, tid, lane, wv, wg, quad, myb, myh);
  else
    run_lstm<false>(x, h0, c0, out, flagsT, flagsBT, hring, lring,
                    Ahi, Alo, bias, s_out, tid, lane, wv, wg, quad, myb, myh);
}

extern "C" void kernel_launch(void* const* d_in, const int* in_sizes, int n_in,
                              void* d_out, int out_size, void* d_ws, size_t ws_size,
                              hipStream_t stream) {
  const float* x   = (const float*)d_in[0];
  const float* Wih = (const float*)d_in[1];
  const float* Whh = (const float*)d_in[2];
  const float* bih = (const float*)d_in[3];
  const float* bhh = (const float*)d_in[4];
  const float* h0  = (const float*)d_in[5];
  const float* c0  = (const float*)d_in[6];
  float* out = (float*)d_out;

  char* ws = (char*)d_ws;
  // layout: [0,1024) flags  [1024] ready  [1028,1044) masks  [2048,3072) flagsB
  //         [4096, +33.5MB) hring  [.., +33.5MB) lring   (~67.1 MB total)
  int* flags  = (int*)ws;
  int* ready  = (int*)(ws + 1024);
  unsigned int* masks = (unsigned int*)(ws + 1028);
  int* flagsB = (int*)(ws + 2048);
  const size_t ringBytes = (size_t)NS * PLANE_ELEMS * sizeof(unsigned short);
  unsigned short* hring = (unsigned short*)(ws + 4096);
  unsigned short* lring = (unsigned short*)(ws + 4096 + ringBytes);

  // zero flag page each launch: kills cross-launch flag/counter staleness
  (void)hipMemsetAsync(ws, 0, 4096, stream);

  lstm_l2<<<dim3(512), dim3(128), 0, stream>>>(
      x, Wih, Whh, bih, bhh, h0, c0, out, flags, flagsB, ready, masks,
      hring, lring);
}